// Round 1
// 173.473 us; speedup vs baseline: 1.0345x; 1.0345x over previous
//
#include <hip/hip_runtime.h>
#include <math.h>

#define NZ    128
#define H1    512
#define H2    1024
#define IMG   784
#define IMGP  896     // layer-3 N padded to 7*128
#define BATCH 4096
#define NGEN  10
#define MPAD  128     // packed-row slack so tail tiles can stage past ng

typedef _Float16 f16;
typedef __attribute__((ext_vector_type(8))) _Float16 half8;
typedef __attribute__((ext_vector_type(4))) float floatx4;

// transpose tile counts for the fused prep kernel
#define NB1 ((NZ / 32) * (H1 / 32) * NGEN)    // 640
#define NB2 ((H1 / 32) * (H2 / 32) * NGEN)    // 5120
#define NB3 ((H2 / 32) * (IMGP / 32) * NGEN)  // 8960

__device__ __forceinline__ void cp16(void* l, const void* g) {
    __builtin_amdgcn_global_load_lds((const __attribute__((address_space(1))) void*)g,
                                     (__attribute__((address_space(3))) void*)l, 16, 0, 0);
}

// ---------------- transpose one 32x32 tile: W [g][K][N] f32 -> Wt [g][NPAD][K] f16 ----------------
template<int K, int N, int NPAD>
__device__ __forceinline__ void t_tile(int idx, const float* __restrict__ W,
                                       f16* __restrict__ Wt, f16 (*L)[36]) {
    constexpr int KT = K / 32, NT = NPAD / 32;
    const int g  = idx / (KT * NT);
    const int r2 = idx % (KT * NT);
    const int k0 = (r2 % KT) * 32;
    const int n0 = (r2 / KT) * 32;
    const int t = threadIdx.x;
    {
        const int kk = t >> 3;
        const int nq = (t & 7) * 4;
        float4 v = make_float4(0.f, 0.f, 0.f, 0.f);
        if (n0 + nq < N)   // N % 4 == 0: quads never straddle
            v = *(const float4*)(W + ((size_t)g * K + (k0 + kk)) * N + n0 + nq);
        L[nq + 0][kk] = (f16)v.x;
        L[nq + 1][kk] = (f16)v.y;
        L[nq + 2][kk] = (f16)v.z;
        L[nq + 3][kk] = (f16)v.w;
    }
    __syncthreads();
    {
        const int nn = t >> 3;
        const int kq = (t & 7) * 4;
        *(ushort4*)(Wt + ((size_t)g * NPAD + (n0 + nn)) * K + k0 + kq) =
            *(const ushort4*)&L[nn][kq];
    }
}

// ---------------- fused prep: block 0 = hist+perm, rest = weight transposes ----------------
__global__ __launch_bounds__(256)
void prep(const float* __restrict__ W1, const float* __restrict__ W2,
          const float* __restrict__ W3, f16* __restrict__ W1t,
          f16* __restrict__ W2t, f16* __restrict__ W3t,
          const int* __restrict__ g_idx, int* __restrict__ seg,
          int* __restrict__ perm) {
    __shared__ f16 L[32][36];
    __shared__ int lc[NGEN];
    __shared__ int lb[NGEN + 1];
    int bid = blockIdx.x;
    if (bid == 0) {
        const int t = threadIdx.x;
        if (t < NGEN) lc[t] = 0;
        __syncthreads();
        int gv[BATCH / 256];
        #pragma unroll
        for (int i = 0; i < BATCH / 256; ++i) {
            gv[i] = g_idx[t + i * 256];
            atomicAdd(&lc[gv[i]], 1);
        }
        __syncthreads();
        if (t == 0) {
            int s = 0;
            for (int g = 0; g < NGEN; ++g) { lb[g] = s; s += lc[g]; }
            lb[NGEN] = s;
        }
        __syncthreads();
        if (t <= NGEN) seg[t] = lb[t];
        if (t < NGEN) lc[t] = lb[t];      // reuse as cursors
        __syncthreads();
        #pragma unroll
        for (int i = 0; i < BATCH / 256; ++i) {
            int p = atomicAdd(&lc[gv[i]], 1);
            perm[p] = t + i * 256;
        }
        return;
    }
    --bid;
    if (bid < NB1) { t_tile<NZ, H1, H1>(bid, W1, W1t, L); return; }
    bid -= NB1;
    if (bid < NB2) { t_tile<H1, H2, H2>(bid, W2, W2t, L); return; }
    bid -= NB2;
    t_tile<H2, IMG, IMGP>(bid, W3, W3t, L);
}

// ---------------- 64x128-tile grouped GEMM ----------------
// Block = (m-tile 64, n-tile 128, gen). 4 waves 2x2, each wave owns 32x64
// (acc[2][4]). Per BK=64 iter per wave: 12 ds_read_b128 + 16 MFMA (was 8+8
// at 64x64) -> LDS traffic per MFMA down 25%, A global re-reads halved.
// LDS XOR-swizzle unchanged: phys k-quad = logical ^ ((row>>1)&7); within
// each 16-lane phase frag reads stay 2-way (free).
// B col map: frag nf -> col wn + (nf>>1)*32 + 2*lm + (nf&1): adjacent col
// pairs per lane -> two float2/uint stores.
// ACT: 0 relu, 1 tanh. SCATTER: 0 -> packed f16 Ch; 1 -> f32 out via perm.
// GATHER: 1 -> A staged from f32 z via perm with in-reg convert (layer 1).
template<int K, int NOUT, int NPADB, int ACT, int SCATTER, int GATHER>
__global__ __launch_bounds__(256)
void gemm(const f16* __restrict__ Ap, const float* __restrict__ Az,
          const f16* __restrict__ Wt, const float* __restrict__ bias,
          f16* __restrict__ Ch, float* __restrict__ Cout,
          const int* __restrict__ seg, const int* __restrict__ perm) {
    const int g  = blockIdx.z;
    const int s0 = seg[g];
    const int ng = seg[g + 1] - s0;
    const int m0 = blockIdx.x * 64;
    if (m0 >= ng) return;                 // block-uniform early exit
    const int n0 = blockIdx.y * 128;

    __shared__ f16 As[64 * 64];
    __shared__ f16 Bs[128 * 64];

    const int tid = threadIdx.x, lane = tid & 63, w = tid >> 6;

    // B staging: wave w stages rows [w*32, w*32+32), 4 cp16.
    const f16* gb[4]; f16* lb[4];
    #pragma unroll
    for (int j = 0; j < 4; ++j) {
        const int r   = w * 32 + j * 8 + (lane >> 3);
        const int swz = ((lane & 7) ^ ((r >> 1) & 7)) * 8;
        gb[j] = Wt + ((size_t)g * NPADB + n0 + r) * K + swz;
        lb[j] = Bs + (w * 32 + j * 8) * 64;
    }

    // A staging: wave w stages rows [w*16, w*16+16), 2 units.
    const f16* ga[2]; f16* la[2];
    const float* gz[2]; f16* aw[2];
    #pragma unroll
    for (int j = 0; j < 2; ++j) {
        const int r   = w * 16 + j * 8 + (lane >> 3);
        const int swz = ((lane & 7) ^ ((r >> 1) & 7)) * 8;
        la[j] = As + (w * 16 + j * 8) * 64;
        if constexpr (GATHER != 0) {
            // gather z row via perm; clamp so last-gen tail tiles never
            // dereference the poison slack of perm[]
            const int pr = min(s0 + m0 + r, BATCH - 1);
            gz[j] = Az + (size_t)perm[pr] * K + (lane & 7) * 8;
            aw[j] = As + (size_t)r * 64 + swz;   // swizzled ds_write dest
        } else {
            ga[j] = Ap + (size_t)(s0 + m0 + r) * K + swz;
        }
    }

    const int wm = (w & 1) * 32, wn = (w >> 1) * 64;
    const int lm = lane & 15, lq = lane >> 4;

    floatx4 acc[2][4] = {};

    #pragma unroll
    for (int kc = 0; kc < K / 64; ++kc) {
        __syncthreads();                  // prior frag reads done: LDS reusable
        #pragma unroll
        for (int j = 0; j < 4; ++j) { cp16(lb[j], gb[j]); gb[j] += 64; }
        if constexpr (GATHER != 0) {
            #pragma unroll
            for (int j = 0; j < 2; ++j) {
                const float4 v0 = *(const float4*)(gz[j]);
                const float4 v1 = *(const float4*)(gz[j] + 4);
                gz[j] += 64;
                half8 h;
                h[0] = (f16)v0.x; h[1] = (f16)v0.y; h[2] = (f16)v0.z; h[3] = (f16)v0.w;
                h[4] = (f16)v1.x; h[5] = (f16)v1.y; h[6] = (f16)v1.z; h[7] = (f16)v1.w;
                *(half8*)aw[j] = h;
            }
        } else {
            #pragma unroll
            for (int j = 0; j < 2; ++j) { cp16(la[j], ga[j]); ga[j] += 64; }
        }
        __syncthreads();                  // staging drained
        #pragma unroll
        for (int ks = 0; ks < 2; ++ks) {
            half8 a[2], b[4];
            #pragma unroll
            for (int mt = 0; mt < 2; ++mt) {
                const int r  = wm + mt * 16 + lm;
                const int pq = (ks * 4 + lq) ^ ((r >> 1) & 7);
                a[mt] = *(const half8*)&As[r * 64 + pq * 8];
            }
            #pragma unroll
            for (int nf = 0; nf < 4; ++nf) {
                const int r  = wn + (nf >> 1) * 32 + 2 * lm + (nf & 1);
                const int pq = (ks * 4 + lq) ^ ((r >> 1) & 7);
                b[nf] = *(const half8*)&Bs[r * 64 + pq * 8];
            }
            #pragma unroll
            for (int mt = 0; mt < 2; ++mt)
                #pragma unroll
                for (int nf = 0; nf < 4; ++nf)
                    acc[mt][nf] = __builtin_amdgcn_mfma_f32_16x16x32_f16(
                        a[mt], b[nf], acc[mt][nf], 0, 0, 0);
        }
    }

    // epilogue: C/D row = (lane>>4)*4 + reg; cols c,c+1 (nf=0,1) and
    // c+32,c+33 (nf=2,3). Even c: pairs never straddle NOUT.
    const int c = n0 + wn + 2 * lm;
    const float* bg = bias + (size_t)g * NOUT;
    const bool in0 = (!SCATTER) || (c < NOUT);
    const bool in1 = (!SCATTER) || (c + 32 < NOUT);
    const float b0 = in0 ? bg[c]      : 0.f;
    const float b1 = in0 ? bg[c + 1]  : 0.f;
    const float b2 = in1 ? bg[c + 32] : 0.f;
    const float b3 = in1 ? bg[c + 33] : 0.f;
    #pragma unroll
    for (int mt = 0; mt < 2; ++mt)
        #pragma unroll
        for (int rr = 0; rr < 4; ++rr) {
            const int gr = m0 + wm + mt * 16 + lq * 4 + rr;
            if (gr >= ng) continue;
            float x0 = acc[mt][0][rr] + b0;
            float x1 = acc[mt][1][rr] + b1;
            float x2 = acc[mt][2][rr] + b2;
            float x3 = acc[mt][3][rr] + b3;
            if (ACT == 0) {
                x0 = fmaxf(x0, 0.f); x1 = fmaxf(x1, 0.f);
                x2 = fmaxf(x2, 0.f); x3 = fmaxf(x3, 0.f);
            } else {                       // tanh, inf-safe
                const float e0 = __expf(2.f * x0);
                const float e1 = __expf(2.f * x1);
                const float e2 = __expf(2.f * x2);
                const float e3 = __expf(2.f * x3);
                x0 = 1.f - 2.f / (e0 + 1.f);
                x1 = 1.f - 2.f / (e1 + 1.f);
                x2 = 1.f - 2.f / (e2 + 1.f);
                x3 = 1.f - 2.f / (e3 + 1.f);
            }
            if (SCATTER) {
                const size_t orow = (size_t)perm[s0 + gr];
                if (in0) *(float2*)&Cout[orow * NOUT + c]      = make_float2(x0, x1);
                if (in1) *(float2*)&Cout[orow * NOUT + c + 32] = make_float2(x2, x3);
            } else {
                union { uint u; f16 h[2]; } o0, o1;
                o0.h[0] = (f16)x0; o0.h[1] = (f16)x1;
                o1.h[0] = (f16)x2; o1.h[1] = (f16)x3;
                *(uint*)&Ch[(size_t)(s0 + gr) * NOUT + c]      = o0.u;
                *(uint*)&Ch[(size_t)(s0 + gr) * NOUT + c + 32] = o1.u;
            }
        }
}

extern "C" void kernel_launch(void* const* d_in, const int* in_sizes, int n_in,
                              void* d_out, int out_size, void* d_ws, size_t ws_size,
                              hipStream_t stream) {
    const float* z    = (const float*)d_in[0];
    const int*   gidx = (const int*)  d_in[1];
    const float* W1   = (const float*)d_in[2];
    const float* b1   = (const float*)d_in[3];
    const float* W2   = (const float*)d_in[4];
    const float* b2   = (const float*)d_in[5];
    const float* W3   = (const float*)d_in[6];
    const float* b3   = (const float*)d_in[7];
    float* out = (float*)d_out;

    char* ws = (char*)d_ws;
    size_t off = 0;
    auto alloc = [&](size_t bytes) { size_t o = off; off = (off + bytes + 255) & ~255ULL; return o; };
    int* seg  = (int*)(ws + alloc((size_t)(NGEN + 1) * 4));
    int* perm = (int*)(ws + alloc((size_t)(BATCH + MPAD) * 4));
    f16* h1p = (f16*)(ws + alloc((size_t)(BATCH + MPAD) * H1 * 2));
    f16* h2p = (f16*)(ws + alloc((size_t)(BATCH + MPAD) * H2 * 2));
    f16* W1t = (f16*)(ws + alloc((size_t)NGEN * H1 * NZ * 2));
    f16* W2t = (f16*)(ws + alloc((size_t)NGEN * H2 * H1 * 2));
    f16* W3t = (f16*)(ws + alloc((size_t)NGEN * IMGP * H2 * 2));

    // K1: hist (1 block) co-scheduled with all weight transposes
    prep<<<dim3(1 + NB1 + NB2 + NB3), dim3(256), 0, stream>>>(
        W1, W2, W3, W1t, W2t, W3t, gidx, seg, perm);

    // grid.x = 16 covers any plausible bucket size (<=1024); empty m-tiles
    // exit on the seg[] read. Active blocks: ~7 m-tiles/gen (ng ~ 410).
    gemm<NZ, H1, H1, 0, 0, 1><<<dim3(16, H1 / 128, NGEN), dim3(256), 0, stream>>>(
        nullptr, z, W1t, b1, h1p, nullptr, seg, perm);
    gemm<H1, H2, H2, 0, 0, 0><<<dim3(16, H2 / 128, NGEN), dim3(256), 0, stream>>>(
        h1p, nullptr, W2t, b2, h2p, nullptr, seg, perm);
    gemm<H2, IMG, IMGP, 1, 1, 0><<<dim3(16, IMGP / 128, NGEN), dim3(256), 0, stream>>>(
        h2p, nullptr, W3t, b3, nullptr, out, seg, perm);
}